// Round 1
// baseline (353.156 us; speedup 1.0000x reference)
//
#include <hip/hip_runtime.h>
#include <stdint.h>
#include <math.h>

#define B_ 256
#define H_ 128
#define S_ 2048

typedef __attribute__((ext_vector_type(8))) short short8;
typedef __attribute__((ext_vector_type(4))) float f32x4;

// ---------- helpers ----------
__device__ __forceinline__ unsigned short f2bf(float f) {
  uint32_t u = __builtin_bit_cast(uint32_t, f);
  u += 0x7fffu + ((u >> 16) & 1u);          // round-to-nearest-even
  return (unsigned short)(u >> 16);
}

__device__ __forceinline__ float tanh_fast(float x) {
  float ax = fabsf(x);
  float e = __expf(-2.0f * ax);
  float t = (1.0f - e) / (1.0f + e);
  return copysignf(t, x);
}

// ---------- ws layout (bytes) ----------
// wsA frags : [0, 98304)          24 tiles x 4 ksteps x 64 lanes x 8 bf16
// flag      : [114688, 114692)
// c1        : [131072, 262144)    [B,H] f32
// c2        : [262144, 393216)    [B,H] f32
// ctx       : [393216, 524288)    [B,H] f32
// attns     : [524288, 2621440)   [B,S] f32
// score     : [2621440, 4718592)  [B,S] f32
#define WS_NEED 4718592u

// Pre-swizzle A-operand fragments (bf16) for mfma_f32_16x16x32_bf16.
// tiles 0..7  : W_a rows 0..127   (stage 1, static operand)
// tiles 8..15 : W2_a rows 0..127  (stage 2)
// tiles 16..23: W_b rows 0..127   (stage 1, dynamic operand)
// frag element: lane l, elem j -> row = tile16 + (l&15), k = 32*t + 8*(l>>4) + j
__global__ __launch_bounds__(256) void prep_wfrags(
    const float* __restrict__ W, const float* __restrict__ W2,
    unsigned short* __restrict__ wsA) {
  int idx = blockIdx.x * 256 + threadIdx.x;   // 24*4*64*8 = 49152 total
  if (idx >= 24 * 4 * 64 * 8) return;
  int j = idx & 7;
  int lane = (idx >> 3) & 63;
  int t = (idx >> 9) & 3;
  int tile = idx >> 11;
  int li = lane & 15;
  int k = t * 32 + (lane >> 4) * 8 + j;
  float val;
  if (tile < 8)        val = W[(tile * 16 + li) * 384 + k];             // W_a
  else if (tile < 16)  val = W2[((tile - 8) * 16 + li) * 256 + k];      // W2_a
  else                 val = W[((tile - 16) * 16 + li) * 384 + 128 + k];// W_b
  wsA[idx] = f2bf(val);
}

// c1[b,h] = sum_k W[h, 256+k] * dec[b,k]
__global__ __launch_bounds__(128) void prep_c1(
    const float* __restrict__ W, const float* __restrict__ dec,
    float* __restrict__ c1) {
  int b = blockIdx.x;
  int h = threadIdx.x;
  __shared__ float sdec[H_];
  sdec[h] = dec[b * H_ + h];
  __syncthreads();
  const float* wr = W + h * 384 + 256;
  float acc = 0.f;
  #pragma unroll 4
  for (int k = 0; k < 128; ++k) acc += wr[k] * sdec[k];
  c1[b * H_ + h] = acc;
}

// Detect mask element width: 0 = int32, 1 = uint8(bool), 2 = float32.
__global__ void detect_mask(const unsigned char* __restrict__ mb, int* __restrict__ flag) {
  __shared__ int sGT1, sNZ;
  if (threadIdx.x == 0) { sGT1 = 0; sNZ = 0; }
  __syncthreads();
  int gt1 = 0, nz = 0;
  for (int i = threadIdx.x; i < 8192; i += 256) {
    unsigned char c = mb[i];
    if (c > 1) gt1 = 1;
    if ((i & 3) && c) nz = 1;
  }
  if (gt1) atomicOr(&sGT1, 1);
  if (nz)  atomicOr(&sNZ, 1);
  __syncthreads();
  if (threadIdx.x == 0) *flag = sGT1 ? 2 : (sNZ ? 1 : 0);
}

// Stage 1: attns[b,s] = sum_h v[h]*tanh( (W_a@static)[h,s] + (W_b@dyn^T)[h,s] + c1[b,h] )
// grid (16, 256): blockIdx.x = 128-wide s-chunk, blockIdx.y = b. 4 waves, 2 s16-tiles/wave.
__global__ __launch_bounds__(256) void stage1(
    const float* __restrict__ sEmb, const float* __restrict__ dEmb,
    const unsigned short* __restrict__ wsA, const float* __restrict__ c1,
    const float* __restrict__ v, float* __restrict__ attns) {
  int b = blockIdx.y;
  int tid = threadIdx.x;
  int lane = tid & 63, w = tid >> 6, g = lane >> 4, li = lane & 15;
  __shared__ float sc1[H_], sv[H_];
  if (tid < 128) { sc1[tid] = c1[b * H_ + tid]; sv[tid] = v[tid]; }
  __syncthreads();

  int schunk = blockIdx.x * 128;
  int s0[2] = { schunk + (2 * w) * 16, schunk + (2 * w + 1) * 16 };

  f32x4 acc[2][8];
  #pragma unroll
  for (int tt = 0; tt < 2; ++tt)
    #pragma unroll
    for (int m = 0; m < 8; ++m) acc[tt][m] = (f32x4)0.0f;

  const size_t sbase = (size_t)b * H_ * S_;
  const size_t dbase = (size_t)b * S_ * H_;

  for (int k0 = 0; k0 < 128; k0 += 32) {
    short8 bS[2], bD[2];
    #pragma unroll
    for (int tt = 0; tt < 2; ++tt) {
      int s = s0[tt] + li;
      const float* sp = sEmb + sbase + (size_t)(k0 + 8 * g) * S_ + s;
      short8 fs;
      #pragma unroll
      for (int j = 0; j < 8; ++j) fs[j] = (short)f2bf(sp[(size_t)j * S_]);
      bS[tt] = fs;
      const f32x4* dp = (const f32x4*)(dEmb + dbase + (size_t)s * H_ + (k0 + 8 * g));
      f32x4 d0 = dp[0], d1 = dp[1];
      short8 fd;
      fd[0] = (short)f2bf(d0.x); fd[1] = (short)f2bf(d0.y);
      fd[2] = (short)f2bf(d0.z); fd[3] = (short)f2bf(d0.w);
      fd[4] = (short)f2bf(d1.x); fd[5] = (short)f2bf(d1.y);
      fd[6] = (short)f2bf(d1.z); fd[7] = (short)f2bf(d1.w);
      bD[tt] = fd;
    }
    const int t = k0 >> 5;
    #pragma unroll
    for (int m = 0; m < 8; ++m) {
      short8 aW = *(const short8*)(wsA + (size_t)((m * 4 + t) * 64 + lane) * 8);
      short8 aB = *(const short8*)(wsA + (size_t)(((16 + m) * 4 + t) * 64 + lane) * 8);
      #pragma unroll
      for (int tt = 0; tt < 2; ++tt) {
        acc[tt][m] = __builtin_amdgcn_mfma_f32_16x16x32_bf16(aW, bS[tt], acc[tt][m], 0, 0, 0);
        acc[tt][m] = __builtin_amdgcn_mfma_f32_16x16x32_bf16(aB, bD[tt], acc[tt][m], 0, 0, 0);
      }
    }
  }

  #pragma unroll
  for (int tt = 0; tt < 2; ++tt) {
    float part = 0.f;
    #pragma unroll
    for (int m = 0; m < 8; ++m)
      #pragma unroll
      for (int r = 0; r < 4; ++r) {
        int h = m * 16 + g * 4 + r;
        part += sv[h] * tanh_fast(acc[tt][m][r] + sc1[h]);
      }
    part += __shfl_xor(part, 16);
    part += __shfl_xor(part, 32);
    if (lane < 16) attns[(size_t)b * S_ + s0[tt] + lane] = part;
  }
}

// Softmax(attns row) + context. grid (4, 256): 4 h-quarters per batch.
__global__ __launch_bounds__(256) void kmid_a(
    const float* __restrict__ attns, const float* __restrict__ sEmb,
    float* __restrict__ ctx) {
  int q = blockIdx.x, b = blockIdx.y;
  int tid = threadIdx.x, lane = tid & 63, w = tid >> 6;
  __shared__ float p[S_];
  __shared__ float wred[4];
  __shared__ float sred;

  float a[8];
  #pragma unroll
  for (int i = 0; i < 8; ++i) a[i] = attns[(size_t)b * S_ + i * 256 + tid];
  float mx = a[0];
  #pragma unroll
  for (int i = 1; i < 8; ++i) mx = fmaxf(mx, a[i]);
  #pragma unroll
  for (int off = 32; off >= 1; off >>= 1) mx = fmaxf(mx, __shfl_xor(mx, off));
  if (lane == 0) wred[w] = mx;
  __syncthreads();
  if (tid == 0) sred = fmaxf(fmaxf(wred[0], wred[1]), fmaxf(wred[2], wred[3]));
  __syncthreads();
  mx = sred;
  __syncthreads();
  float sum = 0.f;
  #pragma unroll
  for (int i = 0; i < 8; ++i) {
    float e = __expf(a[i] - mx);
    p[i * 256 + tid] = e;
    sum += e;
  }
  #pragma unroll
  for (int off = 32; off >= 1; off >>= 1) sum += __shfl_xor(sum, off);
  if (lane == 0) wred[w] = sum;
  __syncthreads();
  if (tid == 0) sred = 1.0f / (wred[0] + wred[1] + wred[2] + wred[3]);
  __syncthreads();
  float inv = sred;

  // context for h in [32q, 32q+32), 8 h per wave
  #pragma unroll
  for (int hh = 0; hh < 8; ++hh) {
    int h = q * 32 + w * 8 + hh;
    const f32x4* xp = (const f32x4*)(sEmb + (size_t)b * H_ * S_ + (size_t)h * S_);
    float av = 0.f;
    #pragma unroll
    for (int it = 0; it < 8; ++it) {
      f32x4 x = xp[it * 64 + lane];
      f32x4 pp = *(const f32x4*)&p[(it * 64 + lane) * 4];
      av += x.x * pp.x + x.y * pp.y + x.z * pp.z + x.w * pp.w;
    }
    #pragma unroll
    for (int off = 32; off >= 1; off >>= 1) av += __shfl_xor(av, off);
    if (lane == 0) ctx[b * H_ + h] = av * inv;
  }
}

// c2[b,h] = sum_k W2[h, 128+k] * ctx[b,k]
__global__ __launch_bounds__(128) void kmid_b(
    const float* __restrict__ W2, const float* __restrict__ ctx,
    float* __restrict__ c2) {
  int b = blockIdx.x;
  int h = threadIdx.x;
  __shared__ float sc[H_];
  sc[h] = ctx[b * H_ + h];
  __syncthreads();
  const float* wr = W2 + h * 256 + 128;
  float acc = 0.f;
  #pragma unroll 4
  for (int k = 0; k < 128; ++k) acc += wr[k] * sc[k];
  c2[b * H_ + h] = acc;
}

// Stage 2: score[b,s] = mask ? -inf : sum_h v2[h]*tanh( (W2_a@static)[h,s] + c2[b,h] )
__global__ __launch_bounds__(256) void stage2(
    const float* __restrict__ sEmb, const unsigned short* __restrict__ wsA,
    const float* __restrict__ c2, const float* __restrict__ v2,
    const unsigned char* __restrict__ mask8, const int* __restrict__ flag,
    float* __restrict__ score) {
  int b = blockIdx.y;
  int tid = threadIdx.x;
  int lane = tid & 63, w = tid >> 6, g = lane >> 4, li = lane & 15;
  __shared__ float sc2[H_], sv2[H_];
  if (tid < 128) { sc2[tid] = c2[b * H_ + tid]; sv2[tid] = v2[tid]; }
  __syncthreads();

  int schunk = blockIdx.x * 128;
  int s0[2] = { schunk + (2 * w) * 16, schunk + (2 * w + 1) * 16 };

  f32x4 acc[2][8];
  #pragma unroll
  for (int tt = 0; tt < 2; ++tt)
    #pragma unroll
    for (int m = 0; m < 8; ++m) acc[tt][m] = (f32x4)0.0f;

  const size_t sbase = (size_t)b * H_ * S_;

  for (int k0 = 0; k0 < 128; k0 += 32) {
    short8 bS[2];
    #pragma unroll
    for (int tt = 0; tt < 2; ++tt) {
      int s = s0[tt] + li;
      const float* sp = sEmb + sbase + (size_t)(k0 + 8 * g) * S_ + s;
      short8 fs;
      #pragma unroll
      for (int j = 0; j < 8; ++j) fs[j] = (short)f2bf(sp[(size_t)j * S_]);
      bS[tt] = fs;
    }
    const int t = k0 >> 5;
    #pragma unroll
    for (int m = 0; m < 8; ++m) {
      short8 aW = *(const short8*)(wsA + (size_t)(((8 + m) * 4 + t) * 64 + lane) * 8);
      #pragma unroll
      for (int tt = 0; tt < 2; ++tt)
        acc[tt][m] = __builtin_amdgcn_mfma_f32_16x16x32_bf16(aW, bS[tt], acc[tt][m], 0, 0, 0);
    }
  }

  int f = *flag;
  #pragma unroll
  for (int tt = 0; tt < 2; ++tt) {
    float part = 0.f;
    #pragma unroll
    for (int m = 0; m < 8; ++m)
      #pragma unroll
      for (int r = 0; r < 4; ++r) {
        int h = m * 16 + g * 4 + r;
        part += sv2[h] * tanh_fast(acc[tt][m][r] + sc2[h]);
      }
    part += __shfl_xor(part, 16);
    part += __shfl_xor(part, 32);
    if (lane < 16) {
      size_t mi = (size_t)b * S_ + s0[tt] + lane;
      bool msk;
      if (f == 1)      msk = mask8[mi] != 0;
      else if (f == 2) msk = ((const float*)mask8)[mi] != 0.0f;
      else             msk = ((const int*)mask8)[mi] != 0;
      score[mi] = msk ? -INFINITY : part;
    }
  }
}

// Final row softmax -> out
__global__ __launch_bounds__(256) void ksoftmax(
    const float* __restrict__ score, float* __restrict__ out) {
  int b = blockIdx.x;
  int tid = threadIdx.x, lane = tid & 63, w = tid >> 6;
  __shared__ float wred[4];
  __shared__ float sred;
  float a[8];
  #pragma unroll
  for (int i = 0; i < 8; ++i) a[i] = score[(size_t)b * S_ + i * 256 + tid];
  float mx = a[0];
  #pragma unroll
  for (int i = 1; i < 8; ++i) mx = fmaxf(mx, a[i]);
  #pragma unroll
  for (int off = 32; off >= 1; off >>= 1) mx = fmaxf(mx, __shfl_xor(mx, off));
  if (lane == 0) wred[w] = mx;
  __syncthreads();
  if (tid == 0) sred = fmaxf(fmaxf(wred[0], wred[1]), fmaxf(wred[2], wred[3]));
  __syncthreads();
  mx = sred;
  __syncthreads();
  float e[8];
  float sum = 0.f;
  #pragma unroll
  for (int i = 0; i < 8; ++i) { e[i] = __expf(a[i] - mx); sum += e[i]; }
  #pragma unroll
  for (int off = 32; off >= 1; off >>= 1) sum += __shfl_xor(sum, off);
  if (lane == 0) wred[w] = sum;
  __syncthreads();
  if (tid == 0) sred = 1.0f / (wred[0] + wred[1] + wred[2] + wred[3]);
  __syncthreads();
  float inv = sred;
  #pragma unroll
  for (int i = 0; i < 8; ++i) out[(size_t)b * S_ + i * 256 + tid] = e[i] * inv;
}

extern "C" void kernel_launch(void* const* d_in, const int* in_sizes, int n_in,
                              void* d_out, int out_size, void* d_ws, size_t ws_size,
                              hipStream_t stream) {
  (void)in_sizes; (void)n_in; (void)out_size;
  if (ws_size < WS_NEED) return;
  const float* sEmb = (const float*)d_in[0];
  const float* dEmb = (const float*)d_in[1];
  const float* dec  = (const float*)d_in[2];
  const unsigned char* mask = (const unsigned char*)d_in[3];
  const float* v    = (const float*)d_in[4];
  const float* W    = (const float*)d_in[5];
  const float* v2   = (const float*)d_in[6];
  const float* W2   = (const float*)d_in[7];

  char* ws = (char*)d_ws;
  unsigned short* wsA = (unsigned short*)(ws);
  int*   flag  = (int*)  (ws + 114688);
  float* c1    = (float*)(ws + 131072);
  float* c2    = (float*)(ws + 262144);
  float* ctx   = (float*)(ws + 393216);
  float* attns = (float*)(ws + 524288);
  float* score = (float*)(ws + 2621440);

  prep_wfrags<<<192, 256, 0, stream>>>(W, W2, wsA);
  prep_c1<<<B_, 128, 0, stream>>>(W, dec, c1);
  detect_mask<<<1, 256, 0, stream>>>(mask, flag);
  stage1<<<dim3(16, B_), 256, 0, stream>>>(sEmb, dEmb, wsA, c1, v, attns);
  kmid_a<<<dim3(4, B_), 256, 0, stream>>>(attns, sEmb, ctx);
  kmid_b<<<B_, 128, 0, stream>>>(W2, ctx, c2);
  stage2<<<dim3(16, B_), 256, 0, stream>>>(sEmb, wsA, c2, v2, mask, flag, score);
  ksoftmax<<<B_, 256, 0, stream>>>(score, (float*)d_out);
}

// Round 2
// 316.698 us; speedup vs baseline: 1.1151x; 1.1151x over previous
//
#include <hip/hip_runtime.h>
#include <stdint.h>
#include <math.h>

#define B_ 256
#define H_ 128
#define S_ 2048

typedef __attribute__((ext_vector_type(8))) short short8;
typedef __attribute__((ext_vector_type(4))) float f32x4;

typedef const __attribute__((address_space(1))) void gvoid_t;
typedef __attribute__((address_space(3))) void lvoid_t;

// ---------- helpers ----------
__device__ __forceinline__ unsigned short f2bf(float f) {
  uint32_t u = __builtin_bit_cast(uint32_t, f);
  u += 0x7fffu + ((u >> 16) & 1u);          // round-to-nearest-even
  return (unsigned short)(u >> 16);
}

__device__ __forceinline__ float tanh_fast(float x) {
  float ax = fabsf(x);
  float e = __expf(-2.0f * ax);
  float t = (1.0f - e) / (1.0f + e);
  return copysignf(t, x);
}

// ---------- ws layout (bytes) ----------
// wsA frags : [0, 98304)          24 tiles x 4 ksteps x 64 lanes x 8 bf16
// flag      : [114688, 114692)
// c1        : [131072, 262144)    [B,H] f32
// c2        : [262144, 393216)    [B,H] f32
// ctx       : [393216, 524288)    [B,H] f32
// attns     : [524288, 2621440)   [B,S] f32
// score     : [2621440, 4718592)  [B,S] f32
#define WS_NEED 4718592u

// Pre-swizzle A-operand fragments (bf16) for mfma_f32_16x16x32_bf16.
// tiles 0..7  : W_a rows 0..127   (stage 1, static operand)
// tiles 8..15 : W2_a rows 0..127  (stage 2)
// tiles 16..23: W_b rows 0..127   (stage 1, dynamic operand)
__global__ __launch_bounds__(256) void prep_wfrags(
    const float* __restrict__ W, const float* __restrict__ W2,
    unsigned short* __restrict__ wsA) {
  int idx = blockIdx.x * 256 + threadIdx.x;   // 24*4*64*8 = 49152 total
  if (idx >= 24 * 4 * 64 * 8) return;
  int j = idx & 7;
  int lane = (idx >> 3) & 63;
  int t = (idx >> 9) & 3;
  int tile = idx >> 11;
  int li = lane & 15;
  int k = t * 32 + (lane >> 4) * 8 + j;
  float val;
  if (tile < 8)        val = W[(tile * 16 + li) * 384 + k];             // W_a
  else if (tile < 16)  val = W2[((tile - 8) * 16 + li) * 256 + k];      // W2_a
  else                 val = W[((tile - 16) * 16 + li) * 384 + 128 + k];// W_b
  wsA[idx] = f2bf(val);
}

// c1[b,h] = sum_k W[h, 256+k] * dec[b,k]
__global__ __launch_bounds__(128) void prep_c1(
    const float* __restrict__ W, const float* __restrict__ dec,
    float* __restrict__ c1) {
  int b = blockIdx.x;
  int h = threadIdx.x;
  __shared__ float sdec[H_];
  sdec[h] = dec[b * H_ + h];
  __syncthreads();
  const float* wr = W + h * 384 + 256;
  float acc = 0.f;
  #pragma unroll 4
  for (int k = 0; k < 128; ++k) acc += wr[k] * sdec[k];
  c1[b * H_ + h] = acc;
}

// Detect mask element width: 0 = int32, 1 = uint8(bool), 2 = float32.
__global__ void detect_mask(const unsigned char* __restrict__ mb, int* __restrict__ flag) {
  __shared__ int sGT1, sNZ;
  if (threadIdx.x == 0) { sGT1 = 0; sNZ = 0; }
  __syncthreads();
  int gt1 = 0, nz = 0;
  for (int i = threadIdx.x; i < 8192; i += 256) {
    unsigned char c = mb[i];
    if (c > 1) gt1 = 1;
    if ((i & 3) && c) nz = 1;
  }
  if (gt1) atomicOr(&sGT1, 1);
  if (nz)  atomicOr(&sNZ, 1);
  __syncthreads();
  if (threadIdx.x == 0) *flag = sGT1 ? 2 : (sNZ ? 1 : 0);
}

// Stage 1: attns[b,s] = sum_h v[h]*tanh( (W_a@static)[h,s] + (W_b@dyn^T)[h,s] + c1[b,h] )
// grid (16, 256). 256 thr = 4 waves; wave w owns local s-cols [32w, 32w+32).
// Static tile [128k][128s] f32 staged in LDS via global_load_lds, source-XOR-swizzled:
//   stored word col c holds global col c ^ (((k>>3)&3)<<3)  -> frag ds_read is 2-way (free).
__global__ __launch_bounds__(256) void stage1(
    const float* __restrict__ sEmb, const float* __restrict__ dEmb,
    const unsigned short* __restrict__ wsA, const float* __restrict__ c1,
    const float* __restrict__ v, float* __restrict__ attns) {
  int b = blockIdx.y;
  int tid = threadIdx.x;
  int lane = tid & 63, w = tid >> 6, g = lane >> 4, li = lane & 15;
  __shared__ float sT[128 * 128];
  __shared__ float sc1[H_], sv[H_];

  const size_t sbase = (size_t)b * H_ * S_;
  const size_t dbase = (size_t)b * S_ * H_;
  const int schunk = blockIdx.x * 128;

  // ---- issue static -> LDS (16 x 1KB per wave, lane-linear dest, swizzled src) ----
  {
    int cblk = 4 * (lane & 31);                 // stored word col of this lane's 16B
    #pragma unroll
    for (int i = 0; i < 16; ++i) {
      int krow = w * 32 + 2 * i + (lane >> 5);
      int gcol = cblk ^ (((krow >> 3) & 3) << 3);
      const float* src = sEmb + sbase + (size_t)krow * S_ + schunk + gcol;
      __builtin_amdgcn_global_load_lds((gvoid_t*)src,
                                       (lvoid_t*)&sT[(w * 32 + 2 * i) * 128],
                                       16, 0, 0);
    }
  }

  // ---- issue dynamic -> regs (2 s-rows per lane-group, all K) ----
  f32x4 dv[4][2][2];
  {
    const float* dr0 = dEmb + dbase + (size_t)(schunk + 32 * w + li) * H_ + 8 * g;
    const float* dr1 = dr0 + (size_t)16 * H_;
    #pragma unroll
    for (int t = 0; t < 4; ++t) {
      dv[t][0][0] = *(const f32x4*)(dr0 + 32 * t);
      dv[t][0][1] = *(const f32x4*)(dr0 + 32 * t + 4);
      dv[t][1][0] = *(const f32x4*)(dr1 + 32 * t);
      dv[t][1][1] = *(const f32x4*)(dr1 + 32 * t + 4);
    }
  }

  if (tid < 128) { sc1[tid] = c1[b * H_ + tid]; sv[tid] = v[tid]; }
  __syncthreads();   // drains global_load_lds (vmcnt) + LDS writes

  // ---- convert dyn to bf16 fragments ----
  short8 dynb[4][2];
  #pragma unroll
  for (int t = 0; t < 4; ++t)
    #pragma unroll
    for (int tt = 0; tt < 2; ++tt) {
      f32x4 a0 = dv[t][tt][0], a1 = dv[t][tt][1];
      short8 fd;
      fd[0] = (short)f2bf(a0.x); fd[1] = (short)f2bf(a0.y);
      fd[2] = (short)f2bf(a0.z); fd[3] = (short)f2bf(a0.w);
      fd[4] = (short)f2bf(a1.x); fd[5] = (short)f2bf(a1.y);
      fd[6] = (short)f2bf(a1.z); fd[7] = (short)f2bf(a1.w);
      dynb[t][tt] = fd;
    }

  // per-lane read bases into the swizzled static tile
  const float* pA = &sT[8 * g * 128 + (((32 * w + li)      ) ^ (g << 3))];
  const float* pB = &sT[8 * g * 128 + (((32 * w + 16 + li) ) ^ (g << 3))];

  f32x4 acc[2][8];
  #pragma unroll
  for (int tt = 0; tt < 2; ++tt)
    #pragma unroll
    for (int m = 0; m < 8; ++m) acc[tt][m] = (f32x4)0.0f;

  #pragma unroll
  for (int t = 0; t < 4; ++t) {
    short8 bS0, bS1;
    #pragma unroll
    for (int j = 0; j < 8; ++j) {
      bS0[j] = (short)f2bf(pA[(32 * t + j) * 128]);
      bS1[j] = (short)f2bf(pB[(32 * t + j) * 128]);
    }
    short8 bD0 = dynb[t][0], bD1 = dynb[t][1];
    #pragma unroll
    for (int m = 0; m < 8; ++m) {
      short8 aW = *(const short8*)(wsA + (size_t)((m * 4 + t) * 64 + lane) * 8);
      short8 aB = *(const short8*)(wsA + (size_t)(((16 + m) * 4 + t) * 64 + lane) * 8);
      acc[0][m] = __builtin_amdgcn_mfma_f32_16x16x32_bf16(aW, bS0, acc[0][m], 0, 0, 0);
      acc[1][m] = __builtin_amdgcn_mfma_f32_16x16x32_bf16(aW, bS1, acc[1][m], 0, 0, 0);
      acc[0][m] = __builtin_amdgcn_mfma_f32_16x16x32_bf16(aB, bD0, acc[0][m], 0, 0, 0);
      acc[1][m] = __builtin_amdgcn_mfma_f32_16x16x32_bf16(aB, bD1, acc[1][m], 0, 0, 0);
    }
  }

  int s0[2] = { schunk + 32 * w, schunk + 32 * w + 16 };
  #pragma unroll
  for (int tt = 0; tt < 2; ++tt) {
    float part = 0.f;
    #pragma unroll
    for (int m = 0; m < 8; ++m)
      #pragma unroll
      for (int r = 0; r < 4; ++r) {
        int h = m * 16 + g * 4 + r;
        part += sv[h] * tanh_fast(acc[tt][m][r] + sc1[h]);
      }
    part += __shfl_xor(part, 16);
    part += __shfl_xor(part, 32);
    if (lane < 16) attns[(size_t)b * S_ + s0[tt] + lane] = part;
  }
}

// Softmax(attns row) + context. grid (4, 256): 4 h-quarters per batch.
__global__ __launch_bounds__(256) void kmid_a(
    const float* __restrict__ attns, const float* __restrict__ sEmb,
    float* __restrict__ ctx) {
  int q = blockIdx.x, b = blockIdx.y;
  int tid = threadIdx.x, lane = tid & 63, w = tid >> 6;
  __shared__ float p[S_];
  __shared__ float wred[4];
  __shared__ float sred;

  float a[8];
  #pragma unroll
  for (int i = 0; i < 8; ++i) a[i] = attns[(size_t)b * S_ + i * 256 + tid];
  float mx = a[0];
  #pragma unroll
  for (int i = 1; i < 8; ++i) mx = fmaxf(mx, a[i]);
  #pragma unroll
  for (int off = 32; off >= 1; off >>= 1) mx = fmaxf(mx, __shfl_xor(mx, off));
  if (lane == 0) wred[w] = mx;
  __syncthreads();
  if (tid == 0) sred = fmaxf(fmaxf(wred[0], wred[1]), fmaxf(wred[2], wred[3]));
  __syncthreads();
  mx = sred;
  __syncthreads();
  float sum = 0.f;
  #pragma unroll
  for (int i = 0; i < 8; ++i) {
    float e = __expf(a[i] - mx);
    p[i * 256 + tid] = e;
    sum += e;
  }
  #pragma unroll
  for (int off = 32; off >= 1; off >>= 1) sum += __shfl_xor(sum, off);
  if (lane == 0) wred[w] = sum;
  __syncthreads();
  if (tid == 0) sred = 1.0f / (wred[0] + wred[1] + wred[2] + wred[3]);
  __syncthreads();
  float inv = sred;

  #pragma unroll
  for (int hh = 0; hh < 8; ++hh) {
    int h = q * 32 + w * 8 + hh;
    const f32x4* xp = (const f32x4*)(sEmb + (size_t)b * H_ * S_ + (size_t)h * S_);
    float av = 0.f;
    #pragma unroll
    for (int it = 0; it < 8; ++it) {
      f32x4 x = xp[it * 64 + lane];
      f32x4 pp = *(const f32x4*)&p[(it * 64 + lane) * 4];
      av += x.x * pp.x + x.y * pp.y + x.z * pp.z + x.w * pp.w;
    }
    #pragma unroll
    for (int off = 32; off >= 1; off >>= 1) av += __shfl_xor(av, off);
    if (lane == 0) ctx[b * H_ + h] = av * inv;
  }
}

// c2[b,h] = sum_k W2[h, 128+k] * ctx[b,k]
__global__ __launch_bounds__(128) void kmid_b(
    const float* __restrict__ W2, const float* __restrict__ ctx,
    float* __restrict__ c2) {
  int b = blockIdx.x;
  int h = threadIdx.x;
  __shared__ float sc[H_];
  sc[h] = ctx[b * H_ + h];
  __syncthreads();
  const float* wr = W2 + h * 256 + 128;
  float acc = 0.f;
  #pragma unroll 4
  for (int k = 0; k < 128; ++k) acc += wr[k] * sc[k];
  c2[b * H_ + h] = acc;
}

// Stage 2: score[b,s] = mask ? -inf : sum_h v2[h]*tanh( (W2_a@static)[h,s] + c2[b,h] )
// Same LDS-staged structure as stage1, minus the dynamic operand.
__global__ __launch_bounds__(256) void stage2(
    const float* __restrict__ sEmb, const unsigned short* __restrict__ wsA,
    const float* __restrict__ c2, const float* __restrict__ v2,
    const unsigned char* __restrict__ mask8, const int* __restrict__ flag,
    float* __restrict__ score) {
  int b = blockIdx.y;
  int tid = threadIdx.x;
  int lane = tid & 63, w = tid >> 6, g = lane >> 4, li = lane & 15;
  __shared__ float sT[128 * 128];
  __shared__ float sc2[H_], sv2[H_];

  const size_t sbase = (size_t)b * H_ * S_;
  const int schunk = blockIdx.x * 128;

  {
    int cblk = 4 * (lane & 31);
    #pragma unroll
    for (int i = 0; i < 16; ++i) {
      int krow = w * 32 + 2 * i + (lane >> 5);
      int gcol = cblk ^ (((krow >> 3) & 3) << 3);
      const float* src = sEmb + sbase + (size_t)krow * S_ + schunk + gcol;
      __builtin_amdgcn_global_load_lds((gvoid_t*)src,
                                       (lvoid_t*)&sT[(w * 32 + 2 * i) * 128],
                                       16, 0, 0);
    }
  }

  if (tid < 128) { sc2[tid] = c2[b * H_ + tid]; sv2[tid] = v2[tid]; }
  __syncthreads();

  const float* pA = &sT[8 * g * 128 + (((32 * w + li)      ) ^ (g << 3))];
  const float* pB = &sT[8 * g * 128 + (((32 * w + 16 + li) ) ^ (g << 3))];

  f32x4 acc[2][8];
  #pragma unroll
  for (int tt = 0; tt < 2; ++tt)
    #pragma unroll
    for (int m = 0; m < 8; ++m) acc[tt][m] = (f32x4)0.0f;

  #pragma unroll
  for (int t = 0; t < 4; ++t) {
    short8 bS0, bS1;
    #pragma unroll
    for (int j = 0; j < 8; ++j) {
      bS0[j] = (short)f2bf(pA[(32 * t + j) * 128]);
      bS1[j] = (short)f2bf(pB[(32 * t + j) * 128]);
    }
    #pragma unroll
    for (int m = 0; m < 8; ++m) {
      short8 aW = *(const short8*)(wsA + (size_t)(((8 + m) * 4 + t) * 64 + lane) * 8);
      acc[0][m] = __builtin_amdgcn_mfma_f32_16x16x32_bf16(aW, bS0, acc[0][m], 0, 0, 0);
      acc[1][m] = __builtin_amdgcn_mfma_f32_16x16x32_bf16(aW, bS1, acc[1][m], 0, 0, 0);
    }
  }

  int f = *flag;
  int s0[2] = { schunk + 32 * w, schunk + 32 * w + 16 };
  #pragma unroll
  for (int tt = 0; tt < 2; ++tt) {
    float part = 0.f;
    #pragma unroll
    for (int m = 0; m < 8; ++m)
      #pragma unroll
      for (int r = 0; r < 4; ++r) {
        int h = m * 16 + g * 4 + r;
        part += sv2[h] * tanh_fast(acc[tt][m][r] + sc2[h]);
      }
    part += __shfl_xor(part, 16);
    part += __shfl_xor(part, 32);
    if (lane < 16) {
      size_t mi = (size_t)b * S_ + s0[tt] + lane;
      bool msk;
      if (f == 1)      msk = mask8[mi] != 0;
      else if (f == 2) msk = ((const float*)mask8)[mi] != 0.0f;
      else             msk = ((const int*)mask8)[mi] != 0;
      score[mi] = msk ? -INFINITY : part;
    }
  }
}

// Final row softmax -> out
__global__ __launch_bounds__(256) void ksoftmax(
    const float* __restrict__ score, float* __restrict__ out) {
  int b = blockIdx.x;
  int tid = threadIdx.x, lane = tid & 63, w = tid >> 6;
  __shared__ float wred[4];
  __shared__ float sred;
  float a[8];
  #pragma unroll
  for (int i = 0; i < 8; ++i) a[i] = score[(size_t)b * S_ + i * 256 + tid];
  float mx = a[0];
  #pragma unroll
  for (int i = 1; i < 8; ++i) mx = fmaxf(mx, a[i]);
  #pragma unroll
  for (int off = 32; off >= 1; off >>= 1) mx = fmaxf(mx, __shfl_xor(mx, off));
  if (lane == 0) wred[w] = mx;
  __syncthreads();
  if (tid == 0) sred = fmaxf(fmaxf(wred[0], wred[1]), fmaxf(wred[2], wred[3]));
  __syncthreads();
  mx = sred;
  __syncthreads();
  float e[8];
  float sum = 0.f;
  #pragma unroll
  for (int i = 0; i < 8; ++i) { e[i] = __expf(a[i] - mx); sum += e[i]; }
  #pragma unroll
  for (int off = 32; off >= 1; off >>= 1) sum += __shfl_xor(sum, off);
  if (lane == 0) wred[w] = sum;
  __syncthreads();
  if (tid == 0) sred = 1.0f / (wred[0] + wred[1] + wred[2] + wred[3]);
  __syncthreads();
  float inv = sred;
  #pragma unroll
  for (int i = 0; i < 8; ++i) out[(size_t)b * S_ + i * 256 + tid] = e[i] * inv;
}

extern "C" void kernel_launch(void* const* d_in, const int* in_sizes, int n_in,
                              void* d_out, int out_size, void* d_ws, size_t ws_size,
                              hipStream_t stream) {
  (void)in_sizes; (void)n_in; (void)out_size;
  if (ws_size < WS_NEED) return;
  const float* sEmb = (const float*)d_in[0];
  const float* dEmb = (const float*)d_in[1];
  const float* dec  = (const float*)d_in[2];
  const unsigned char* mask = (const unsigned char*)d_in[3];
  const float* v    = (const float*)d_in[4];
  const float* W    = (const float*)d_in[5];
  const float* v2   = (const float*)d_in[6];
  const float* W2   = (const float*)d_in[7];

  char* ws = (char*)d_ws;
  unsigned short* wsA = (unsigned short*)(ws);
  int*   flag  = (int*)  (ws + 114688);
  float* c1    = (float*)(ws + 131072);
  float* c2    = (float*)(ws + 262144);
  float* ctx   = (float*)(ws + 393216);
  float* attns = (float*)(ws + 524288);
  float* score = (float*)(ws + 2621440);

  prep_wfrags<<<192, 256, 0, stream>>>(W, W2, wsA);
  prep_c1<<<B_, 128, 0, stream>>>(W, dec, c1);
  detect_mask<<<1, 256, 0, stream>>>(mask, flag);
  stage1<<<dim3(16, B_), 256, 0, stream>>>(sEmb, dEmb, wsA, c1, v, attns);
  kmid_a<<<dim3(4, B_), 256, 0, stream>>>(attns, sEmb, ctx);
  kmid_b<<<B_, 128, 0, stream>>>(W2, ctx, c2);
  stage2<<<dim3(16, B_), 256, 0, stream>>>(sEmb, wsA, c2, v2, mask, flag, score);
  ksoftmax<<<B_, 256, 0, stream>>>(score, (float*)d_out);
}